// Round 12
// baseline (2027.892 us; speedup 1.0000x reference)
//
#include <hip/hip_runtime.h>
#include <math.h>

#define NN 50000
#define NE 800000
#define NCOLS 1088   // 256 q | 256 k | 256 v | 256 qt | 64 skip   (cols are h*64+d order)

typedef long long i64;
typedef unsigned short u16;
typedef short bf16x8 __attribute__((ext_vector_type(8)));
typedef unsigned short u16x8 __attribute__((ext_vector_type(8)));
typedef float f32x4 __attribute__((ext_vector_type(4)));

static __device__ __forceinline__ float bf2f(u16 u) {
  union { float f; unsigned b; } x; x.b = ((unsigned)u) << 16; return x.f;
}
static __device__ __forceinline__ u16 f2bf(float f) {
  union { float f; unsigned b; } x; x.f = f;
  unsigned r = x.b + 0x7FFFu + ((x.b >> 16) & 1u);
  return (u16)(r >> 16);
}

// ---------------- edge-index dtype probe + extraction ----------------
__global__ void detect_i64(const int* __restrict__ ei32, int* __restrict__ flag) {
  int i = blockIdx.x * blockDim.x + threadIdx.x;
  if (i < 2048) {
    if (ei32[2 * i + 1] != 0) atomicOr(flag, 1);  // 1 -> data is int32
  }
}

__global__ void extract_edges(const void* __restrict__ ei, const int* __restrict__ flag,
                              int* __restrict__ src32, int* __restrict__ dst32, int ne) {
  int is32 = *flag;
  int i = blockIdx.x * blockDim.x + threadIdx.x;
  int st = gridDim.x * blockDim.x;
  if (is32) {
    const int* p = (const int*)ei;
    for (; i < ne; i += st) { src32[i] = p[i]; dst32[i] = p[ne + i]; }
  } else {
    const i64* p = (const i64*)ei;
    for (; i < ne; i += st) { src32[i] = (int)p[i]; dst32[i] = (int)p[ne + i]; }
  }
}

// ---------------- CSR build ----------------
__global__ void hist_kernel(const int* __restrict__ dst, int* __restrict__ deg, int ne) {
  int i = blockIdx.x * blockDim.x + threadIdx.x;
  int st = gridDim.x * blockDim.x;
  for (; i < ne; i += st) atomicAdd(&deg[dst[i]], 1);
}

#define SCHUNK 1024
__global__ void scanA(const int* __restrict__ deg, int* __restrict__ row_ptr,
                      int* __restrict__ csum, int n) {
  __shared__ int buf[SCHUNK];
  int c = blockIdx.x, t = threadIdx.x;
  int idx = c * SCHUNK + t;
  int v = (idx < n) ? deg[idx] : 0;
  buf[t] = v;
  __syncthreads();
  for (int off = 1; off < SCHUNK; off <<= 1) {
    int x = (t >= off) ? buf[t - off] : 0;
    __syncthreads();
    buf[t] += x;
    __syncthreads();
  }
  if (idx < n) row_ptr[idx + 1] = buf[t];
  if (t == SCHUNK - 1) csum[c] = buf[t];
}

__global__ void scanB(int* __restrict__ csum, int nchunks) {
  if (threadIdx.x == 0 && blockIdx.x == 0) {
    int run = 0;
    for (int c = 0; c < nchunks; ++c) { int v = csum[c]; csum[c] = run; run += v; }
  }
}

__global__ void scanC(int* __restrict__ row_ptr, const int* __restrict__ csum, int n) {
  int c = blockIdx.x, t = threadIdx.x;
  int idx = c * SCHUNK + t;
  if (idx < n) row_ptr[idx + 1] += csum[c];
  if (idx == 0) row_ptr[0] = 0;
}

__global__ void scatter_kernel(const int* __restrict__ src, const int* __restrict__ dst,
                               const int* __restrict__ row_ptr, int* __restrict__ cursor,
                               int* __restrict__ src_sorted, int* __restrict__ eid_sorted, int ne) {
  int i = blockIdx.x * blockDim.x + threadIdx.x;
  int st = gridDim.x * blockDim.x;
  for (; i < ne; i += st) {
    int d = dst[i];
    int pos = row_ptr[d] + atomicAdd(&cursor[d], 1);
    src_sorted[pos] = src[i];
    eid_sorted[pos] = i;
  }
}

// Deterministic order: sort each node's edge list by eid.
__global__ void sort_lists(const int* __restrict__ row_ptr, int* __restrict__ src_sorted,
                           int* __restrict__ eid_sorted, int n) {
  int node = blockIdx.x * blockDim.x + threadIdx.x;
  if (node >= n) return;
  int beg = row_ptr[node], end = row_ptr[node + 1];
  for (int a = beg + 1; a < end; ++a) {
    int e = eid_sorted[a], s = src_sorted[a];
    int b = a - 1;
    while (b >= beg && eid_sorted[b] > e) {
      eid_sorted[b + 1] = eid_sorted[b];
      src_sorted[b + 1] = src_sorted[b];
      --b;
    }
    eid_sorted[b + 1] = e; src_sorted[b + 1] = s;
  }
}

// ---------------- ea pre-gather into CSR order ----------
__global__ void ea_gather(const int* __restrict__ eid_sorted, const float* __restrict__ ea,
                          float* __restrict__ ea_csr, int ne) {
  long total = (long)ne * 16;
  long st = (long)gridDim.x * blockDim.x;
  for (long i = (long)blockIdx.x * blockDim.x + threadIdx.x; i < total; i += st) {
    int j = (int)(i >> 4);
    int c = (int)(i & 15);
    int e = eid_sorted[j];
    ((float4*)ea_csr)[i] = ((const float4*)ea)[(size_t)e * 16 + c];
  }
}

// ---------------- split fp32 -> bf16 hi + bf16 lo ----------------
__global__ void cvt_split(const float* __restrict__ in, u16* __restrict__ hi,
                          u16* __restrict__ lo, int nElem) {
  int i = blockIdx.x * blockDim.x + threadIdx.x;
  int st = gridDim.x * blockDim.x;
  for (; i < nElem; i += st) {
    float v = in[i];
    u16 h = f2bf(v);
    hi[i] = h;
    lo[i] = f2bf(v - bf2f(h));
  }
}

// ---------------- weight prep (fp32, head-major cols) ----------------
__global__ void prep_wt(const float* __restrict__ Wq, const float* __restrict__ Wk,
                        const float* __restrict__ Wv, const float* __restrict__ We,
                        const float* __restrict__ Wsk, float* __restrict__ Wt, int fin) {
  int i = blockIdx.x * blockDim.x + threadIdx.x;
  if (i >= NCOLS * fin) return;
  int col = i / fin, k = i % fin;
  float val;
  if (col < 768) {
    const float* W = (col < 256) ? Wq : (col < 512) ? Wk : Wv;
    val = W[k * 256 + (col & 255)];
  } else if (col < 1024) {
    int idx = col - 768; int h = idx >> 6, ce = idx & 63;
    float a = 0.f;
    for (int d = 0; d < 64; ++d) a += Wq[k * 256 + h * 64 + d] * We[ce * 256 + h * 64 + d];
    val = a;
  } else {
    val = Wsk[k * 64 + (col - 1024)];
  }
  Wt[(size_t)col * fin + k] = val;
}

__global__ void prep_bias(const float* __restrict__ bq, const float* __restrict__ bk,
                          const float* __restrict__ bv, const float* __restrict__ We,
                          const float* __restrict__ bsk, float* __restrict__ bb) {
  int col = blockIdx.x * blockDim.x + threadIdx.x;
  if (col >= NCOLS) return;
  float val;
  if (col < 768) {
    const float* b = (col < 256) ? bq : (col < 512) ? bk : bv;
    val = b[col & 255];
  } else if (col < 1024) {
    int idx = col - 768; int h = idx >> 6, ce = idx & 63;
    float a = 0.f;
    for (int d = 0; d < 64; ++d) a += bq[h * 64 + d] * We[ce * 256 + h * 64 + d];
    val = a;
  } else {
    val = bsk[col - 1024];
  }
  bb[col] = val;
}

// Wpost for the deferred West GEMM: Wt2[col][k], k = h*64+ce, value We[ce][h*64+col]
__global__ void prep_wpost(const float* __restrict__ We, float* __restrict__ Wt2) {
  int i = blockIdx.x * blockDim.x + threadIdx.x;
  if (i >= 64 * 256) return;
  int col = i >> 8, k = i & 255;
  int h = k >> 6, ce = k & 63;
  Wt2[i] = We[ce * 256 + h * 64 + col];
}

// ---------------- split-bf16 MFMA node GEMM: out = X @ Wt^T + b ----------------
__global__ __launch_bounds__(256) void node_gemm_mfma(
    const u16* __restrict__ Xhi, const u16* __restrict__ Xlo,
    const u16* __restrict__ Whi, const u16* __restrict__ Wlo,
    const float* __restrict__ bb,
    float* __restrict__ qq_tab, float* __restrict__ kv_tab,
    float* __restrict__ skip_tab, int n, int fin) {
  __shared__ __align__(16) u16 Ah[64][72];
  __shared__ __align__(16) u16 Al[64][72];
  __shared__ __align__(16) u16 Bh[64][72];
  __shared__ __align__(16) u16 Bl[64][72];
  int tid = threadIdx.x, wave = tid >> 6, lane = tid & 63;
  int c0 = blockIdx.x * 64, m0 = blockIdx.y * 64;
  f32x4 acc[4];
  #pragma unroll
  for (int i = 0; i < 4; ++i) acc[i] = (f32x4){0.f, 0.f, 0.f, 0.f};

  int lr = tid >> 2, sg = (tid & 3) * 16;
  for (int k0 = 0; k0 < fin; k0 += 64) {
    u16x8 z = {0, 0, 0, 0, 0, 0, 0, 0};
    u16x8 a0 = z, a1 = z, l0 = z, l1 = z;
    if (m0 + lr < n) {
      const u16* ph = &Xhi[(size_t)(m0 + lr) * fin + k0 + sg];
      a0 = *(const u16x8*)ph; a1 = *(const u16x8*)(ph + 8);
      const u16* pl = &Xlo[(size_t)(m0 + lr) * fin + k0 + sg];
      l0 = *(const u16x8*)pl; l1 = *(const u16x8*)(pl + 8);
    }
    *(u16x8*)&Ah[lr][sg] = a0; *(u16x8*)&Ah[lr][sg + 8] = a1;
    *(u16x8*)&Al[lr][sg] = l0; *(u16x8*)&Al[lr][sg + 8] = l1;
    {
      const u16* ph = &Whi[(size_t)(c0 + lr) * fin + k0 + sg];
      *(u16x8*)&Bh[lr][sg] = *(const u16x8*)ph;
      *(u16x8*)&Bh[lr][sg + 8] = *(const u16x8*)(ph + 8);
      const u16* pl = &Wlo[(size_t)(c0 + lr) * fin + k0 + sg];
      *(u16x8*)&Bl[lr][sg] = *(const u16x8*)pl;
      *(u16x8*)&Bl[lr][sg + 8] = *(const u16x8*)(pl + 8);
    }
    __syncthreads();
    int arow = wave * 16 + (lane & 15);
    int kb = (lane >> 4) * 8;
    #pragma unroll
    for (int ks = 0; ks < 2; ++ks) {
      bf16x8 ah = *(const bf16x8*)&Ah[arow][ks * 32 + kb];
      bf16x8 al_ = *(const bf16x8*)&Al[arow][ks * 32 + kb];
      #pragma unroll
      for (int nf = 0; nf < 4; ++nf) {
        bf16x8 bh = *(const bf16x8*)&Bh[nf * 16 + (lane & 15)][ks * 32 + kb];
        bf16x8 bl = *(const bf16x8*)&Bl[nf * 16 + (lane & 15)][ks * 32 + kb];
        acc[nf] = __builtin_amdgcn_mfma_f32_16x16x32_bf16(ah, bh, acc[nf], 0, 0, 0);
        acc[nf] = __builtin_amdgcn_mfma_f32_16x16x32_bf16(ah, bl, acc[nf], 0, 0, 0);
        acc[nf] = __builtin_amdgcn_mfma_f32_16x16x32_bf16(al_, bh, acc[nf], 0, 0, 0);
      }
    }
    __syncthreads();
  }
  int rbase = m0 + wave * 16 + (lane >> 4) * 4;
  int cl = lane & 15;
  #pragma unroll
  for (int nf = 0; nf < 4; ++nf) {
    int col = c0 + nf * 16 + cl;
    float bias = bb[col];
    #pragma unroll
    for (int r = 0; r < 4; ++r) {
      int row = rbase + r;
      if (row >= n) continue;
      float val = acc[nf][r] + bias;
      if (col < 256)        qq_tab[(size_t)row * 512 + col] = val;           // q
      else if (col < 768)   kv_tab[(size_t)row * 512 + col - 256] = val;     // k | v
      else if (col < 1024)  qq_tab[(size_t)row * 512 + col - 512] = val;     // qt
      else                  skip_tab[(size_t)row * 64 + col - 1024] = val;
    }
  }
}

// ---------------- phase A: edge scores le[e][h] = qt[dst]·ea (pure stream) ----------------
__global__ __launch_bounds__(256) void edge_scores(
    const int* __restrict__ row_ptr, const int* __restrict__ eid_sorted,
    const float* __restrict__ ea, const float* __restrict__ ea_csr, int use_csr,
    const float* __restrict__ qq_tab, float* __restrict__ al_tab, int n) {
  int tid = threadIdx.x;
  int wave = tid >> 6, lane = tid & 63;
  int h = lane >> 4, c16 = lane & 15;
  int node = blockIdx.x * 4 + wave;
  if (node >= n) return;
  int beg = row_ptr[node], end = row_ptr[node + 1];
  const float4* qq4 = (const float4*)qq_tab;
  const float4* ec4 = (const float4*)ea_csr;
  const float4* e4p = (const float4*)ea;
  float4 t4 = qq4[(size_t)node * 128 + 64 + lane];
  for (int j = beg; j < end; ++j) {
    float4 E;
    if (use_csr) E = ec4[(size_t)j * 16 + c16];
    else { int e_ = eid_sorted[j]; E = e4p[(size_t)e_ * 16 + c16]; }
    float p = t4.x * E.x + t4.y * E.y + t4.z * E.z + t4.w * E.w;
    p += __shfl_xor(p, 1);
    p += __shfl_xor(p, 2);
    p += __shfl_xor(p, 4);
    p += __shfl_xor(p, 8);
    if (c16 == 0) al_tab[(size_t)j * 4 + h] = p;
  }
}

// ---------------- phase B: gather-only attention (no ea; kv stays L3-resident) --------------
// alpha = (q·k[src] + le)/8; online softmax; av accum; store alpha + (m,s) per (node,head).
__global__ __launch_bounds__(256) void attn_B(
    const int* __restrict__ row_ptr, const int* __restrict__ src_sorted,
    const float* __restrict__ qq_tab, const float* __restrict__ kv_tab,
    float* __restrict__ al_tab, float* __restrict__ ms_tab,
    float* __restrict__ avs_tab, int n) {
  int tid = threadIdx.x;
  int wave = tid >> 6, lane = tid & 63;
  int h = lane >> 4, c16 = lane & 15;
  const float4* qq4 = (const float4*)qq_tab;
  const float4* kv4 = (const float4*)kv_tab;

  int node = blockIdx.x * 4 + wave;
  if (node >= n) return;
  int beg = row_ptr[node];
  int deg = row_ptr[node + 1] - beg;

  float4 q4 = qq4[(size_t)node * 128 + lane];
  float m = -INFINITY, s = 0.f;
  float4 av = make_float4(0.f, 0.f, 0.f, 0.f);

#define LDB(j_, K_, V_, L_)                                   \
  {                                                           \
    int jc = (j_); int jm = beg + deg - 1;                    \
    if (jc > jm) jc = jm;                                     \
    int s_ = src_sorted[jc];                                  \
    const float4* kr = kv4 + (size_t)s_ * 128;                \
    K_ = kr[lane]; V_ = kr[64 + lane];                        \
    L_ = al_tab[(size_t)jc * 4 + h];                          \
  }

#define PROCB(j_, K_, V_, L_)                                 \
  {                                                           \
    float p = q4.x * K_.x + q4.y * K_.y + q4.z * K_.z + q4.w * K_.w; \
    p += __shfl_xor(p, 1);                                    \
    p += __shfl_xor(p, 2);                                    \
    p += __shfl_xor(p, 4);                                    \
    p += __shfl_xor(p, 8);                                    \
    float alpha = (p + L_) * 0.125f;                          \
    if (c16 == 0) al_tab[(size_t)(j_) * 4 + h] = alpha;       \
    float d_ = alpha - m;                                     \
    float e_ = __expf(-fabsf(d_));                            \
    float sc = d_ > 0.f ? e_ : 1.f;                           \
    float pp = d_ > 0.f ? 1.f : e_;                           \
    m = fmaxf(m, alpha);                                      \
    s = s * sc + pp;                                          \
    av.x = av.x * sc + pp * V_.x; av.y = av.y * sc + pp * V_.y; \
    av.z = av.z * sc + pp * V_.z; av.w = av.w * sc + pp * V_.w; \
  }

  if (deg > 0) {
    float4 KA, VA, KB, VB;
    float LA, LB;
    LDB(beg + 0, KA, VA, LA);
    LDB(beg + 1, KB, VB, LB);
    int t = 0;
    for (; t + 1 < deg; t += 2) {
      {
        float4 nK, nV; float nL;
        LDB(beg + t + 2, nK, nV, nL);
        PROCB(beg + t, KA, VA, LA);
        KA = nK; VA = nV; LA = nL;
      }
      {
        float4 nK, nV; float nL;
        LDB(beg + t + 3, nK, nV, nL);
        PROCB(beg + t + 1, KB, VB, LB);
        KB = nK; VB = nV; LB = nL;
      }
    }
    if (t < deg) PROCB(beg + t, KA, VA, LA);
  }

  float inv = s > 0.f ? 1.f / s : 0.f;
  float4 avn = make_float4(av.x * inv, av.y * inv, av.z * inv, av.w * inv);

  if (c16 == 0) {
    ms_tab[(size_t)node * 8 + h * 2] = m;
    ms_tab[(size_t)node * 8 + h * 2 + 1] = s;
  }

  avn.x += __shfl_xor(avn.x, 16); avn.y += __shfl_xor(avn.y, 16);
  avn.z += __shfl_xor(avn.z, 16); avn.w += __shfl_xor(avn.w, 16);
  avn.x += __shfl_xor(avn.x, 32); avn.y += __shfl_xor(avn.y, 32);
  avn.z += __shfl_xor(avn.z, 32); avn.w += __shfl_xor(avn.w, 32);
  if (lane < 16)
    ((float4*)avs_tab)[(size_t)node * 16 + c16] = avn;
}

// ---------------- phase C: awn = (1/s)·Σ exp(α−m)·ea  (pure stream) ----------------
__global__ __launch_bounds__(256) void aw_accum(
    const int* __restrict__ row_ptr, const int* __restrict__ eid_sorted,
    const float* __restrict__ ea, const float* __restrict__ ea_csr, int use_csr,
    const float* __restrict__ al_tab, const float* __restrict__ ms_tab,
    float* __restrict__ awn_tab, int n) {
  int tid = threadIdx.x;
  int wave = tid >> 6, lane = tid & 63;
  int h = lane >> 4, c16 = lane & 15;
  int node = blockIdx.x * 4 + wave;
  if (node >= n) return;
  int beg = row_ptr[node], end = row_ptr[node + 1];
  const float4* ec4 = (const float4*)ea_csr;
  const float4* e4p = (const float4*)ea;
  float m = ms_tab[(size_t)node * 8 + h * 2];
  float s = ms_tab[(size_t)node * 8 + h * 2 + 1];
  float inv = s > 0.f ? 1.f / s : 0.f;
  float4 aw = make_float4(0.f, 0.f, 0.f, 0.f);
  for (int j = beg; j < end; ++j) {
    float alpha = al_tab[(size_t)j * 4 + h];
    float4 E;
    if (use_csr) E = ec4[(size_t)j * 16 + c16];
    else { int e_ = eid_sorted[j]; E = e4p[(size_t)e_ * 16 + c16]; }
    float u = __expf(alpha - m);
    aw.x = fmaf(u, E.x, aw.x); aw.y = fmaf(u, E.y, aw.y);
    aw.z = fmaf(u, E.z, aw.z); aw.w = fmaf(u, E.w, aw.w);
  }
  ((float4*)awn_tab)[(size_t)node * 64 + lane] =
      make_float4(aw.x * inv, aw.y * inv, aw.z * inv, aw.w * inv);
}

// ---------------- post GEMM + fused head-mean/skip/GN/GELU (+ optional bf16 split out) ----
__global__ __launch_bounds__(256) void post_gn(
    const float* __restrict__ A, const float* __restrict__ B,
    const float* __restrict__ avs, const float* __restrict__ skip,
    const float* __restrict__ gnw, const float* __restrict__ gnb,
    float* __restrict__ out_f32, u16* __restrict__ out_hi, u16* __restrict__ out_lo, int n) {
  __shared__ __align__(16) float Xs[128][68];
  __shared__ __align__(16) float Ws[64][68];
  int tid = threadIdx.x;
  int tx = tid & 15, ty = tid >> 4;
  int m0 = blockIdx.x * 128;
  float acc[8][4];
  #pragma unroll
  for (int i = 0; i < 8; ++i)
    #pragma unroll
    for (int j = 0; j < 4; ++j) acc[i][j] = 0.f;

  for (int k0 = 0; k0 < 256; k0 += 64) {
    #pragma unroll
    for (int p = 0; p < 8; ++p) {
      int r = ty + 16 * p;
      float4 xv = make_float4(0.f, 0.f, 0.f, 0.f);
      if (m0 + r < n) xv = *(const float4*)&A[(size_t)(m0 + r) * 256 + k0 + tx * 4];
      *(float4*)&Xs[r][tx * 4] = xv;
    }
    #pragma unroll
    for (int p = 0; p < 4; ++p) {
      int r = ty + 16 * p;
      float4 wv = *(const float4*)&B[(size_t)r * 256 + k0 + tx * 4];
      *(float4*)&Ws[r][tx * 4] = wv;
    }
    __syncthreads();
    #pragma unroll 4
    for (int kk = 0; kk < 64; kk += 4) {
      float4 a[8], b[4];
      #pragma unroll
      for (int i = 0; i < 8; ++i) a[i] = *(const float4*)&Xs[ty + 16 * i][kk];
      #pragma unroll
      for (int j = 0; j < 4; ++j) b[j] = *(const float4*)&Ws[tx + 16 * j][kk];
      #pragma unroll
      for (int i = 0; i < 8; ++i)
        #pragma unroll
        for (int j = 0; j < 4; ++j) {
          acc[i][j] = fmaf(a[i].x, b[j].x, acc[i][j]);
          acc[i][j] = fmaf(a[i].y, b[j].y, acc[i][j]);
          acc[i][j] = fmaf(a[i].z, b[j].z, acc[i][j]);
          acc[i][j] = fmaf(a[i].w, b[j].w, acc[i][j]);
        }
    }
    __syncthreads();
  }
  #pragma unroll
  for (int j = 0; j < 4; ++j)
    #pragma unroll
    for (int i = 0; i < 8; ++i)
      Xs[ty + 16 * i][tx + 16 * j] = acc[i][j];
  __syncthreads();

  #pragma unroll
  for (int rep = 0; rep < 8; ++rep) {
    int id = tid + 256 * rep;
    int rl = id >> 4, grp = id & 15;
    int row = m0 + rl;
    if (row >= n) continue;
    float4 a = ((const float4*)avs)[(size_t)row * 16 + grp];
    float4 sk = ((const float4*)skip)[(size_t)row * 16 + grp];
    float4 gw = ((const float4*)gnw)[grp];
    float4 gb = ((const float4*)gnb)[grp];
    float p0 = Xs[rl][grp * 4 + 0], p1 = Xs[rl][grp * 4 + 1];
    float p2 = Xs[rl][grp * 4 + 2], p3 = Xs[rl][grp * 4 + 3];
    float v0 = 0.25f * (a.x + p0) + sk.x;
    float v1 = 0.25f * (a.y + p1) + sk.y;
    float v2 = 0.25f * (a.z + p2) + sk.z;
    float v3 = 0.25f * (a.w + p3) + sk.w;
    float mu = ((v0 + v1) + (v2 + v3)) * 0.25f;
    float d0 = v0 - mu, d1 = v1 - mu, d2 = v2 - mu, d3 = v3 - mu;
    float var = ((d0 * d0 + d1 * d1) + (d2 * d2 + d3 * d3)) * 0.25f;
    float r = rsqrtf(var + 1e-5f);
    float y0 = d0 * r * gw.x + gb.x;
    float y1 = d1 * r * gw.y + gb.y;
    float y2 = d2 * r * gw.z + gb.z;
    float y3 = d3 * r * gw.w + gb.w;
    #define GELU(y) (0.5f * (y) * (1.0f + erff((y) * 0.70710678118654752f)))
    float g0 = GELU(y0), g1 = GELU(y1), g2 = GELU(y2), g3 = GELU(y3);
    if (out_f32) {
      float4 o; o.x = g0; o.y = g1; o.z = g2; o.w = g3;
      ((float4*)out_f32)[(size_t)row * 16 + grp] = o;
    } else {
      u16 h0 = f2bf(g0), h1 = f2bf(g1), h2 = f2bf(g2), h3 = f2bf(g3);
      ushort4 hv; hv.x = h0; hv.y = h1; hv.z = h2; hv.w = h3;
      *(ushort4*)&out_hi[(size_t)row * 64 + grp * 4] = hv;
      ushort4 lv;
      lv.x = f2bf(g0 - bf2f(h0)); lv.y = f2bf(g1 - bf2f(h1));
      lv.z = f2bf(g2 - bf2f(h2)); lv.w = f2bf(g3 - bf2f(h3));
      *(ushort4*)&out_lo[(size_t)row * 64 + grp * 4] = lv;
    }
  }
}

// ---------------- host ----------------
extern "C" void kernel_launch(void* const* d_in, const int* in_sizes, int n_in,
                              void* d_out, int out_size, void* d_ws, size_t ws_size,
                              hipStream_t stream) {
  (void)in_sizes; (void)n_in;
  const float* x = (const float*)d_in[0];
  const void* ei = d_in[1];
  const float* ea = (const float*)d_in[2];
  const float *Wq[3], *bq[3], *Wk[3], *bk[3], *Wv[3], *bv[3], *We[3], *Wsk[3], *bsk[3];
  for (int L = 0; L < 3; ++L) {
    int b = 3 + 9 * L;
    Wq[L] = (const float*)d_in[b + 0]; bq[L] = (const float*)d_in[b + 1];
    Wk[L] = (const float*)d_in[b + 2]; bk[L] = (const float*)d_in[b + 3];
    Wv[L] = (const float*)d_in[b + 4]; bv[L] = (const float*)d_in[b + 5];
    We[L] = (const float*)d_in[b + 6]; Wsk[L] = (const float*)d_in[b + 7];
    bsk[L] = (const float*)d_in[b + 8];
  }
  const float* gnw = (const float*)d_in[30];
  const float* gnb = (const float*)d_in[31];

  char* p = (char*)d_ws;
  auto alloc = [&](size_t bytes) -> void* {
    void* r = (void*)p;
    p += (bytes + 255) & ~(size_t)255;
    return r;
  };
  float* qq_tab = (float*)alloc((size_t)NN * 512 * 4);
  float* kv_tab = (float*)alloc((size_t)NN * 512 * 4);
  float* skip_tab = (float*)alloc((size_t)NN * 64 * 4);
  float* avs_tab = (float*)alloc((size_t)NN * 64 * 4);
  float* awn_tab = (float*)alloc((size_t)NN * 256 * 4);
  float* al_tab = (float*)alloc((size_t)NE * 4 * 4);
  float* ms_tab = (float*)alloc((size_t)NN * 8 * 4);
  u16* xhi = (u16*)alloc((size_t)NN * 128 * 2);
  u16* xlo = (u16*)alloc((size_t)NN * 128 * 2);
  u16* hhi = (u16*)alloc((size_t)NN * 64 * 2);
  u16* hlo = (u16*)alloc((size_t)NN * 64 * 2);
  int* row_ptr = (int*)alloc((size_t)(NN + 1) * 4);
  int* deg = (int*)alloc((size_t)NN * 4);
  int* cursor = (int*)alloc((size_t)NN * 4);
  int* csum = (int*)alloc(1024 * 4);
  int* src_sorted = (int*)alloc((size_t)NE * 4);
  int* eid_sorted = (int*)alloc((size_t)NE * 4);
  int* src32 = (int*)alloc((size_t)NE * 4);
  int* dst32 = (int*)alloc((size_t)NE * 4);
  int* flag = (int*)alloc(256);
  float* Wt[3]; float* bb[3]; float* Wt2[3];
  u16 *whi[3], *wlo[3];
  Wt[0] = (float*)alloc((size_t)NCOLS * 128 * 4);
  Wt[1] = (float*)alloc((size_t)NCOLS * 64 * 4);
  Wt[2] = (float*)alloc((size_t)NCOLS * 64 * 4);
  whi[0] = (u16*)alloc((size_t)NCOLS * 128 * 2);
  wlo[0] = (u16*)alloc((size_t)NCOLS * 128 * 2);
  whi[1] = (u16*)alloc((size_t)NCOLS * 64 * 2);
  wlo[1] = (u16*)alloc((size_t)NCOLS * 64 * 2);
  whi[2] = (u16*)alloc((size_t)NCOLS * 64 * 2);
  wlo[2] = (u16*)alloc((size_t)NCOLS * 64 * 2);
  for (int L = 0; L < 3; ++L) bb[L] = (float*)alloc((size_t)NCOLS * 4);
  for (int L = 0; L < 3; ++L) Wt2[L] = (float*)alloc((size_t)64 * 256 * 4);

  // Workspace overflow guard (all-zero output == error 1.65625 signature).
  if ((size_t)(p - (char*)d_ws) > ws_size) {
    hipMemsetAsync(d_out, 0, (size_t)out_size * 4, stream);
    return;
  }

  // Optional ea_csr buffer (205 MB).
  float* ea_csr = nullptr;
  int use_csr = 0;
  {
    size_t need = (size_t)(p - (char*)d_ws) + (size_t)NE * 64 * 4 + 256;
    if (need <= ws_size) {
      ea_csr = (float*)alloc((size_t)NE * 64 * 4);
      use_csr = 1;
    }
  }

  hipMemsetAsync(deg, 0, (size_t)NN * 4, stream);
  hipMemsetAsync(cursor, 0, (size_t)NN * 4, stream);
  hipMemsetAsync(flag, 0, 4, stream);

  detect_i64<<<8, 256, 0, stream>>>((const int*)ei, flag);
  extract_edges<<<2048, 256, 0, stream>>>(ei, flag, src32, dst32, NE);

  hist_kernel<<<2048, 256, 0, stream>>>(dst32, deg, NE);
  int nchunks = (NN + SCHUNK - 1) / SCHUNK;
  scanA<<<nchunks, SCHUNK, 0, stream>>>(deg, row_ptr, csum, NN);
  scanB<<<1, 64, 0, stream>>>(csum, nchunks);
  scanC<<<nchunks, SCHUNK, 0, stream>>>(row_ptr, csum, NN);
  scatter_kernel<<<2048, 256, 0, stream>>>(src32, dst32, row_ptr, cursor, src_sorted, eid_sorted, NE);
  sort_lists<<<(NN + 255) / 256, 256, 0, stream>>>(row_ptr, src_sorted, eid_sorted, NN);
  if (use_csr)
    ea_gather<<<2048, 256, 0, stream>>>(eid_sorted, ea, ea_csr, NE);

  cvt_split<<<2048, 256, 0, stream>>>(x, xhi, xlo, NN * 128);

  for (int L = 0; L < 3; ++L) {
    int fin = (L == 0) ? 128 : 64;
    prep_wt<<<(NCOLS * fin + 255) / 256, 256, 0, stream>>>(Wq[L], Wk[L], Wv[L], We[L], Wsk[L], Wt[L], fin);
    prep_bias<<<(NCOLS + 255) / 256, 256, 0, stream>>>(bq[L], bk[L], bv[L], We[L], bsk[L], bb[L]);
    prep_wpost<<<64, 256, 0, stream>>>(We[L], Wt2[L]);
    cvt_split<<<(NCOLS * fin + 255) / 256, 256, 0, stream>>>(Wt[L], whi[L], wlo[L], NCOLS * fin);
  }

  const u16* hi_in = xhi;
  const u16* lo_in = xlo;
  int nblk = (NN + 3) / 4;
  for (int L = 0; L < 3; ++L) {
    int fin = (L == 0) ? 128 : 64;
    dim3 g(17, (NN + 63) / 64);
    node_gemm_mfma<<<g, 256, 0, stream>>>(hi_in, lo_in, whi[L], wlo[L], bb[L],
                                          qq_tab, kv_tab, skip_tab, NN, fin);
    edge_scores<<<nblk, 256, 0, stream>>>(row_ptr, eid_sorted, ea, ea_csr, use_csr,
                                          qq_tab, al_tab, NN);
    attn_B<<<nblk, 256, 0, stream>>>(row_ptr, src_sorted, qq_tab, kv_tab,
                                     al_tab, ms_tab, avs_tab, NN);
    aw_accum<<<nblk, 256, 0, stream>>>(row_ptr, eid_sorted, ea, ea_csr, use_csr,
                                       al_tab, ms_tab, awn_tab, NN);
    post_gn<<<(NN + 127) / 128, 256, 0, stream>>>(
        awn_tab, Wt2[L], avs_tab, skip_tab, gnw, gnb,
        (L == 2) ? (float*)d_out : nullptr,
        (L < 2) ? hhi : nullptr, (L < 2) ? hlo : nullptr, NN);
    hi_in = hhi; lo_in = hlo;
  }
}

// Round 13
// 1528.012 us; speedup vs baseline: 1.3271x; 1.3271x over previous
//
#include <hip/hip_runtime.h>
#include <math.h>

#define NN 50000
#define NE 800000
#define NCOLS 1088   // 256 q | 256 k | 256 v | 256 qt | 64 skip   (cols are h*64+d order)

typedef long long i64;
typedef unsigned short u16;
typedef short bf16x8 __attribute__((ext_vector_type(8)));
typedef unsigned short u16x8 __attribute__((ext_vector_type(8)));
typedef float f32x4 __attribute__((ext_vector_type(4)));

static __device__ __forceinline__ float bf2f(u16 u) {
  union { float f; unsigned b; } x; x.b = ((unsigned)u) << 16; return x.f;
}
static __device__ __forceinline__ u16 f2bf(float f) {
  union { float f; unsigned b; } x; x.f = f;
  unsigned r = x.b + 0x7FFFu + ((x.b >> 16) & 1u);
  return (u16)(r >> 16);
}

// ---------------- edge-index dtype probe + extraction ----------------
__global__ void detect_i64(const int* __restrict__ ei32, int* __restrict__ flag) {
  int i = blockIdx.x * blockDim.x + threadIdx.x;
  if (i < 2048) {
    if (ei32[2 * i + 1] != 0) atomicOr(flag, 1);  // 1 -> data is int32
  }
}

__global__ void extract_edges(const void* __restrict__ ei, const int* __restrict__ flag,
                              int* __restrict__ src32, int* __restrict__ dst32, int ne) {
  int is32 = *flag;
  int i = blockIdx.x * blockDim.x + threadIdx.x;
  int st = gridDim.x * blockDim.x;
  if (is32) {
    const int* p = (const int*)ei;
    for (; i < ne; i += st) { src32[i] = p[i]; dst32[i] = p[ne + i]; }
  } else {
    const i64* p = (const i64*)ei;
    for (; i < ne; i += st) { src32[i] = (int)p[i]; dst32[i] = (int)p[ne + i]; }
  }
}

// ---------------- CSR build ----------------
__global__ void hist_kernel(const int* __restrict__ dst, int* __restrict__ deg, int ne) {
  int i = blockIdx.x * blockDim.x + threadIdx.x;
  int st = gridDim.x * blockDim.x;
  for (; i < ne; i += st) atomicAdd(&deg[dst[i]], 1);
}

#define SCHUNK 1024
__global__ void scanA(const int* __restrict__ deg, int* __restrict__ row_ptr,
                      int* __restrict__ csum, int n) {
  __shared__ int buf[SCHUNK];
  int c = blockIdx.x, t = threadIdx.x;
  int idx = c * SCHUNK + t;
  int v = (idx < n) ? deg[idx] : 0;
  buf[t] = v;
  __syncthreads();
  for (int off = 1; off < SCHUNK; off <<= 1) {
    int x = (t >= off) ? buf[t - off] : 0;
    __syncthreads();
    buf[t] += x;
    __syncthreads();
  }
  if (idx < n) row_ptr[idx + 1] = buf[t];
  if (t == SCHUNK - 1) csum[c] = buf[t];
}

__global__ void scanB(int* __restrict__ csum, int nchunks) {
  if (threadIdx.x == 0 && blockIdx.x == 0) {
    int run = 0;
    for (int c = 0; c < nchunks; ++c) { int v = csum[c]; csum[c] = run; run += v; }
  }
}

__global__ void scanC(int* __restrict__ row_ptr, const int* __restrict__ csum, int n) {
  int c = blockIdx.x, t = threadIdx.x;
  int idx = c * SCHUNK + t;
  if (idx < n) row_ptr[idx + 1] += csum[c];
  if (idx == 0) row_ptr[0] = 0;
}

__global__ void scatter_kernel(const int* __restrict__ src, const int* __restrict__ dst,
                               const int* __restrict__ row_ptr, int* __restrict__ cursor,
                               int* __restrict__ src_sorted, int* __restrict__ eid_sorted, int ne) {
  int i = blockIdx.x * blockDim.x + threadIdx.x;
  int st = gridDim.x * blockDim.x;
  for (; i < ne; i += st) {
    int d = dst[i];
    int pos = row_ptr[d] + atomicAdd(&cursor[d], 1);
    src_sorted[pos] = src[i];
    eid_sorted[pos] = i;
  }
}

// Deterministic order: sort each node's edge list by eid.
__global__ void sort_lists(const int* __restrict__ row_ptr, int* __restrict__ src_sorted,
                           int* __restrict__ eid_sorted, int n) {
  int node = blockIdx.x * blockDim.x + threadIdx.x;
  if (node >= n) return;
  int beg = row_ptr[node], end = row_ptr[node + 1];
  for (int a = beg + 1; a < end; ++a) {
    int e = eid_sorted[a], s = src_sorted[a];
    int b = a - 1;
    while (b >= beg && eid_sorted[b] > e) {
      eid_sorted[b + 1] = eid_sorted[b];
      src_sorted[b + 1] = src_sorted[b];
      --b;
    }
    eid_sorted[b + 1] = e; src_sorted[b + 1] = s;
  }
}

// ---------------- ea pre-gather into CSR order ----------
__global__ void ea_gather(const int* __restrict__ eid_sorted, const float* __restrict__ ea,
                          float* __restrict__ ea_csr, int ne) {
  long total = (long)ne * 16;
  long st = (long)gridDim.x * blockDim.x;
  for (long i = (long)blockIdx.x * blockDim.x + threadIdx.x; i < total; i += st) {
    int j = (int)(i >> 4);
    int c = (int)(i & 15);
    int e = eid_sorted[j];
    ((float4*)ea_csr)[i] = ((const float4*)ea)[(size_t)e * 16 + c];
  }
}

// ---------------- split fp32 -> bf16 hi + bf16 lo (for x input) ----------------
__global__ void cvt_split(const float* __restrict__ in, u16* __restrict__ hi,
                          u16* __restrict__ lo, int nElem) {
  int i = blockIdx.x * blockDim.x + threadIdx.x;
  int st = gridDim.x * blockDim.x;
  for (; i < nElem; i += st) {
    float v = in[i];
    u16 h = f2bf(v);
    hi[i] = h;
    lo[i] = f2bf(v - bf2f(h));
  }
}

// ---------------- weight prep: directly emit split hi/lo (head-major cols) ----------------
__global__ void prep_wt_split(const float* __restrict__ Wq, const float* __restrict__ Wk,
                              const float* __restrict__ Wv, const float* __restrict__ We,
                              const float* __restrict__ Wsk,
                              u16* __restrict__ whi, u16* __restrict__ wlo, int fin) {
  int i = blockIdx.x * blockDim.x + threadIdx.x;
  if (i >= NCOLS * fin) return;
  int col = i / fin, k = i % fin;
  float val;
  if (col < 768) {
    const float* W = (col < 256) ? Wq : (col < 512) ? Wk : Wv;
    val = W[k * 256 + (col & 255)];
  } else if (col < 1024) {
    int idx = col - 768; int h = idx >> 6, ce = idx & 63;
    float a = 0.f;
    for (int d = 0; d < 64; ++d) a += Wq[k * 256 + h * 64 + d] * We[ce * 256 + h * 64 + d];
    val = a;
  } else {
    val = Wsk[k * 64 + (col - 1024)];
  }
  size_t idx2 = (size_t)col * fin + k;
  u16 h = f2bf(val);
  whi[idx2] = h;
  wlo[idx2] = f2bf(val - bf2f(h));
}

__global__ void prep_bias(const float* __restrict__ bq, const float* __restrict__ bk,
                          const float* __restrict__ bv, const float* __restrict__ We,
                          const float* __restrict__ bsk, float* __restrict__ bb) {
  int col = blockIdx.x * blockDim.x + threadIdx.x;
  if (col >= NCOLS) return;
  float val;
  if (col < 768) {
    const float* b = (col < 256) ? bq : (col < 512) ? bk : bv;
    val = b[col & 255];
  } else if (col < 1024) {
    int idx = col - 768; int h = idx >> 6, ce = idx & 63;
    float a = 0.f;
    for (int d = 0; d < 64; ++d) a += bq[h * 64 + d] * We[ce * 256 + h * 64 + d];
    val = a;
  } else {
    val = bsk[col - 1024];
  }
  bb[col] = val;
}

// Wpost for the deferred West GEMM: Wt2[col][k], k = h*64+ce, value We[ce][h*64+col]
__global__ void prep_wpost(const float* __restrict__ We, float* __restrict__ Wt2) {
  int i = blockIdx.x * blockDim.x + threadIdx.x;
  if (i >= 64 * 256) return;
  int col = i >> 8, k = i & 255;
  int h = k >> 6, ce = k & 63;
  Wt2[i] = We[ce * 256 + h * 64 + col];
}

// ---------------- split-bf16 MFMA node GEMM: out = X @ Wt^T + b ----------------
__global__ __launch_bounds__(256) void node_gemm_mfma(
    const u16* __restrict__ Xhi, const u16* __restrict__ Xlo,
    const u16* __restrict__ Whi, const u16* __restrict__ Wlo,
    const float* __restrict__ bb,
    float* __restrict__ qq_tab, float* __restrict__ kv_tab,
    float* __restrict__ skip_tab, int n, int fin) {
  __shared__ __align__(16) u16 Ah[64][72];
  __shared__ __align__(16) u16 Al[64][72];
  __shared__ __align__(16) u16 Bh[64][72];
  __shared__ __align__(16) u16 Bl[64][72];
  int tid = threadIdx.x, wave = tid >> 6, lane = tid & 63;
  int c0 = blockIdx.x * 64, m0 = blockIdx.y * 64;
  f32x4 acc[4];
  #pragma unroll
  for (int i = 0; i < 4; ++i) acc[i] = (f32x4){0.f, 0.f, 0.f, 0.f};

  int lr = tid >> 2, sg = (tid & 3) * 16;
  for (int k0 = 0; k0 < fin; k0 += 64) {
    u16x8 z = {0, 0, 0, 0, 0, 0, 0, 0};
    u16x8 a0 = z, a1 = z, l0 = z, l1 = z;
    if (m0 + lr < n) {
      const u16* ph = &Xhi[(size_t)(m0 + lr) * fin + k0 + sg];
      a0 = *(const u16x8*)ph; a1 = *(const u16x8*)(ph + 8);
      const u16* pl = &Xlo[(size_t)(m0 + lr) * fin + k0 + sg];
      l0 = *(const u16x8*)pl; l1 = *(const u16x8*)(pl + 8);
    }
    *(u16x8*)&Ah[lr][sg] = a0; *(u16x8*)&Ah[lr][sg + 8] = a1;
    *(u16x8*)&Al[lr][sg] = l0; *(u16x8*)&Al[lr][sg + 8] = l1;
    {
      const u16* ph = &Whi[(size_t)(c0 + lr) * fin + k0 + sg];
      *(u16x8*)&Bh[lr][sg] = *(const u16x8*)ph;
      *(u16x8*)&Bh[lr][sg + 8] = *(const u16x8*)(ph + 8);
      const u16* pl = &Wlo[(size_t)(c0 + lr) * fin + k0 + sg];
      *(u16x8*)&Bl[lr][sg] = *(const u16x8*)pl;
      *(u16x8*)&Bl[lr][sg + 8] = *(const u16x8*)(pl + 8);
    }
    __syncthreads();
    int arow = wave * 16 + (lane & 15);
    int kb = (lane >> 4) * 8;
    #pragma unroll
    for (int ks = 0; ks < 2; ++ks) {
      bf16x8 ah = *(const bf16x8*)&Ah[arow][ks * 32 + kb];
      bf16x8 al_ = *(const bf16x8*)&Al[arow][ks * 32 + kb];
      #pragma unroll
      for (int nf = 0; nf < 4; ++nf) {
        bf16x8 bh = *(const bf16x8*)&Bh[nf * 16 + (lane & 15)][ks * 32 + kb];
        bf16x8 bl = *(const bf16x8*)&Bl[nf * 16 + (lane & 15)][ks * 32 + kb];
        acc[nf] = __builtin_amdgcn_mfma_f32_16x16x32_bf16(ah, bh, acc[nf], 0, 0, 0);
        acc[nf] = __builtin_amdgcn_mfma_f32_16x16x32_bf16(ah, bl, acc[nf], 0, 0, 0);
        acc[nf] = __builtin_amdgcn_mfma_f32_16x16x32_bf16(al_, bh, acc[nf], 0, 0, 0);
      }
    }
    __syncthreads();
  }
  int rbase = m0 + wave * 16 + (lane >> 4) * 4;
  int cl = lane & 15;
  #pragma unroll
  for (int nf = 0; nf < 4; ++nf) {
    int col = c0 + nf * 16 + cl;
    float bias = bb[col];
    #pragma unroll
    for (int r = 0; r < 4; ++r) {
      int row = rbase + r;
      if (row >= n) continue;
      float val = acc[nf][r] + bias;
      if (col < 256)        qq_tab[(size_t)row * 512 + col] = val;           // q
      else if (col < 768)   kv_tab[(size_t)row * 512 + col - 256] = val;     // k | v
      else if (col < 1024)  qq_tab[(size_t)row * 512 + col - 512] = val;     // qt
      else                  skip_tab[(size_t)row * 64 + col - 1024] = val;
    }
  }
}

// ---------------- attention v6: 1 node/wave, no West matvec ----------------
__global__ __launch_bounds__(256) void attn_kernel_v6(
    const int* __restrict__ row_ptr, const int* __restrict__ src_sorted,
    const int* __restrict__ eid_sorted, const float* __restrict__ ea,
    const float* __restrict__ ea_csr, int use_csr,
    const float* __restrict__ qq_tab, const float* __restrict__ kv_tab,
    float* __restrict__ avs_tab, float* __restrict__ awn_tab, int n) {
  int tid = threadIdx.x;
  int wave = tid >> 6, lane = tid & 63;
  int c16 = lane & 15;
  const float4* qq4 = (const float4*)qq_tab;
  const float4* kv4 = (const float4*)kv_tab;
  const float4* ec4 = (const float4*)ea_csr;
  const float4* e4p = (const float4*)ea;

  int node = blockIdx.x * 4 + wave;
  if (node >= n) return;
  int beg = row_ptr[node];
  int deg = row_ptr[node + 1] - beg;

  float4 q4 = qq4[(size_t)node * 128 + lane];
  float4 t4 = qq4[(size_t)node * 128 + 64 + lane];

  float m = -INFINITY, s = 0.f;
  float4 av = make_float4(0.f, 0.f, 0.f, 0.f);
  float4 aw = make_float4(0.f, 0.f, 0.f, 0.f);

#define LDE(j_, K_, V_, E_)                                   \
  {                                                           \
    int jc = (j_); int jm = beg + deg - 1;                    \
    if (jc > jm) jc = jm;                                     \
    int s_ = src_sorted[jc];                                  \
    const float4* kr = kv4 + (size_t)s_ * 128;                \
    K_ = kr[lane]; V_ = kr[64 + lane];                        \
    if (use_csr) E_ = ec4[(size_t)jc * 16 + c16];             \
    else { int e_ = eid_sorted[jc];                           \
           E_ = e4p[(size_t)e_ * 16 + c16]; }                 \
  }

#define PROC(K_, V_, E_)                                      \
  {                                                           \
    float p = q4.x * K_.x + q4.y * K_.y + q4.z * K_.z + q4.w * K_.w \
            + t4.x * E_.x + t4.y * E_.y + t4.z * E_.z + t4.w * E_.w; \
    p += __shfl_xor(p, 1);                                    \
    p += __shfl_xor(p, 2);                                    \
    p += __shfl_xor(p, 4);                                    \
    p += __shfl_xor(p, 8);                                    \
    p *= 0.125f;                                              \
    float d_ = p - m;                                         \
    float e_ = __expf(-fabsf(d_));                            \
    float sc = d_ > 0.f ? e_ : 1.f;                           \
    float pp = d_ > 0.f ? 1.f : e_;                           \
    m = fmaxf(m, p);                                          \
    s = s * sc + pp;                                          \
    av.x = av.x * sc + pp * V_.x; av.y = av.y * sc + pp * V_.y; \
    av.z = av.z * sc + pp * V_.z; av.w = av.w * sc + pp * V_.w; \
    aw.x = aw.x * sc + pp * E_.x; aw.y = aw.y * sc + pp * E_.y; \
    aw.z = aw.z * sc + pp * E_.z; aw.w = aw.w * sc + pp * E_.w; \
  }

  if (deg > 0) {
    float4 KA, VA, EA, KB, VB, EB;
    LDE(beg + 0, KA, VA, EA);
    LDE(beg + 1, KB, VB, EB);
    int t = 0;
    for (; t + 1 < deg; t += 2) {
      {
        float4 nK, nV, nE;
        LDE(beg + t + 2, nK, nV, nE);
        PROC(KA, VA, EA);
        KA = nK; VA = nV; EA = nE;
      }
      {
        float4 nK, nV, nE;
        LDE(beg + t + 3, nK, nV, nE);
        PROC(KB, VB, EB);
        KB = nK; VB = nV; EB = nE;
      }
    }
    if (t < deg) PROC(KA, VA, EA);
  }

  float inv = s > 0.f ? 1.f / s : 0.f;
  float4 awn = make_float4(aw.x * inv, aw.y * inv, aw.z * inv, aw.w * inv);
  float4 avn = make_float4(av.x * inv, av.y * inv, av.z * inv, av.w * inv);

  ((float4*)awn_tab)[(size_t)node * 64 + lane] = awn;

  avn.x += __shfl_xor(avn.x, 16); avn.y += __shfl_xor(avn.y, 16);
  avn.z += __shfl_xor(avn.z, 16); avn.w += __shfl_xor(avn.w, 16);
  avn.x += __shfl_xor(avn.x, 32); avn.y += __shfl_xor(avn.y, 32);
  avn.z += __shfl_xor(avn.z, 32); avn.w += __shfl_xor(avn.w, 32);
  if (lane < 16)
    ((float4*)avs_tab)[(size_t)node * 16 + c16] = avn;
}

// ---------------- post GEMM + fused head-mean/skip/GN/GELU (+ optional bf16 split out) ----
__global__ __launch_bounds__(256) void post_gn(
    const float* __restrict__ A, const float* __restrict__ B,
    const float* __restrict__ avs, const float* __restrict__ skip,
    const float* __restrict__ gnw, const float* __restrict__ gnb,
    float* __restrict__ out_f32, u16* __restrict__ out_hi, u16* __restrict__ out_lo, int n) {
  __shared__ __align__(16) float Xs[128][68];
  __shared__ __align__(16) float Ws[64][68];
  int tid = threadIdx.x;
  int tx = tid & 15, ty = tid >> 4;
  int m0 = blockIdx.x * 128;
  float acc[8][4];
  #pragma unroll
  for (int i = 0; i < 8; ++i)
    #pragma unroll
    for (int j = 0; j < 4; ++j) acc[i][j] = 0.f;

  for (int k0 = 0; k0 < 256; k0 += 64) {
    #pragma unroll
    for (int p = 0; p < 8; ++p) {
      int r = ty + 16 * p;
      float4 xv = make_float4(0.f, 0.f, 0.f, 0.f);
      if (m0 + r < n) xv = *(const float4*)&A[(size_t)(m0 + r) * 256 + k0 + tx * 4];
      *(float4*)&Xs[r][tx * 4] = xv;
    }
    #pragma unroll
    for (int p = 0; p < 4; ++p) {
      int r = ty + 16 * p;
      float4 wv = *(const float4*)&B[(size_t)r * 256 + k0 + tx * 4];
      *(float4*)&Ws[r][tx * 4] = wv;
    }
    __syncthreads();
    #pragma unroll 4
    for (int kk = 0; kk < 64; kk += 4) {
      float4 a[8], b[4];
      #pragma unroll
      for (int i = 0; i < 8; ++i) a[i] = *(const float4*)&Xs[ty + 16 * i][kk];
      #pragma unroll
      for (int j = 0; j < 4; ++j) b[j] = *(const float4*)&Ws[tx + 16 * j][kk];
      #pragma unroll
      for (int i = 0; i < 8; ++i)
        #pragma unroll
        for (int j = 0; j < 4; ++j) {
          acc[i][j] = fmaf(a[i].x, b[j].x, acc[i][j]);
          acc[i][j] = fmaf(a[i].y, b[j].y, acc[i][j]);
          acc[i][j] = fmaf(a[i].z, b[j].z, acc[i][j]);
          acc[i][j] = fmaf(a[i].w, b[j].w, acc[i][j]);
        }
    }
    __syncthreads();
  }
  #pragma unroll
  for (int j = 0; j < 4; ++j)
    #pragma unroll
    for (int i = 0; i < 8; ++i)
      Xs[ty + 16 * i][tx + 16 * j] = acc[i][j];
  __syncthreads();

  #pragma unroll
  for (int rep = 0; rep < 8; ++rep) {
    int id = tid + 256 * rep;
    int rl = id >> 4, grp = id & 15;
    int row = m0 + rl;
    if (row >= n) continue;
    float4 a = ((const float4*)avs)[(size_t)row * 16 + grp];
    float4 sk = ((const float4*)skip)[(size_t)row * 16 + grp];
    float4 gw = ((const float4*)gnw)[grp];
    float4 gb = ((const float4*)gnb)[grp];
    float p0 = Xs[rl][grp * 4 + 0], p1 = Xs[rl][grp * 4 + 1];
    float p2 = Xs[rl][grp * 4 + 2], p3 = Xs[rl][grp * 4 + 3];
    float v0 = 0.25f * (a.x + p0) + sk.x;
    float v1 = 0.25f * (a.y + p1) + sk.y;
    float v2 = 0.25f * (a.z + p2) + sk.z;
    float v3 = 0.25f * (a.w + p3) + sk.w;
    float mu = ((v0 + v1) + (v2 + v3)) * 0.25f;
    float d0 = v0 - mu, d1 = v1 - mu, d2 = v2 - mu, d3 = v3 - mu;
    float var = ((d0 * d0 + d1 * d1) + (d2 * d2 + d3 * d3)) * 0.25f;
    float r = rsqrtf(var + 1e-5f);
    float y0 = d0 * r * gw.x + gb.x;
    float y1 = d1 * r * gw.y + gb.y;
    float y2 = d2 * r * gw.z + gb.z;
    float y3 = d3 * r * gw.w + gb.w;
    #define GELU(y) (0.5f * (y) * (1.0f + erff((y) * 0.70710678118654752f)))
    float g0 = GELU(y0), g1 = GELU(y1), g2 = GELU(y2), g3 = GELU(y3);
    if (out_f32) {
      float4 o; o.x = g0; o.y = g1; o.z = g2; o.w = g3;
      ((float4*)out_f32)[(size_t)row * 16 + grp] = o;
    } else {
      u16 h0 = f2bf(g0), h1 = f2bf(g1), h2 = f2bf(g2), h3 = f2bf(g3);
      ushort4 hv; hv.x = h0; hv.y = h1; hv.z = h2; hv.w = h3;
      *(ushort4*)&out_hi[(size_t)row * 64 + grp * 4] = hv;
      ushort4 lv;
      lv.x = f2bf(g0 - bf2f(h0)); lv.y = f2bf(g1 - bf2f(h1));
      lv.z = f2bf(g2 - bf2f(h2)); lv.w = f2bf(g3 - bf2f(h3));
      *(ushort4*)&out_lo[(size_t)row * 64 + grp * 4] = lv;
    }
  }
}

// ---------------- host ----------------
extern "C" void kernel_launch(void* const* d_in, const int* in_sizes, int n_in,
                              void* d_out, int out_size, void* d_ws, size_t ws_size,
                              hipStream_t stream) {
  (void)in_sizes; (void)n_in;
  const float* x = (const float*)d_in[0];
  const void* ei = d_in[1];
  const float* ea = (const float*)d_in[2];
  const float *Wq[3], *bq[3], *Wk[3], *bk[3], *Wv[3], *bv[3], *We[3], *Wsk[3], *bsk[3];
  for (int L = 0; L < 3; ++L) {
    int b = 3 + 9 * L;
    Wq[L] = (const float*)d_in[b + 0]; bq[L] = (const float*)d_in[b + 1];
    Wk[L] = (const float*)d_in[b + 2]; bk[L] = (const float*)d_in[b + 3];
    Wv[L] = (const float*)d_in[b + 4]; bv[L] = (const float*)d_in[b + 5];
    We[L] = (const float*)d_in[b + 6]; Wsk[L] = (const float*)d_in[b + 7];
    bsk[L] = (const float*)d_in[b + 8];
  }
  const float* gnw = (const float*)d_in[30];
  const float* gnb = (const float*)d_in[31];

  char* p = (char*)d_ws;
  auto alloc = [&](size_t bytes) -> void* {
    void* r = (void*)p;
    p += (bytes + 255) & ~(size_t)255;
    return r;
  };
  float* qq_tab = (float*)alloc((size_t)NN * 512 * 4);
  float* kv_tab = (float*)alloc((size_t)NN * 512 * 4);
  float* skip_tab = (float*)alloc((size_t)NN * 64 * 4);
  float* avs_tab = (float*)alloc((size_t)NN * 64 * 4);
  float* awn_tab = (float*)alloc((size_t)NN * 256 * 4);
  u16* xhi = (u16*)alloc((size_t)NN * 128 * 2);
  u16* xlo = (u16*)alloc((size_t)NN * 128 * 2);
  u16* hhi = (u16*)alloc((size_t)NN * 64 * 2);
  u16* hlo = (u16*)alloc((size_t)NN * 64 * 2);
  int* row_ptr = (int*)alloc((size_t)(NN + 1) * 4);
  int* deg = (int*)alloc((size_t)NN * 4);
  int* cursor = (int*)alloc((size_t)NN * 4);
  int* csum = (int*)alloc(1024 * 4);
  int* src_sorted = (int*)alloc((size_t)NE * 4);
  int* eid_sorted = (int*)alloc((size_t)NE * 4);
  int* src32 = (int*)alloc((size_t)NE * 4);
  int* dst32 = (int*)alloc((size_t)NE * 4);
  int* flag = (int*)alloc(256);
  float* bb[3]; float* Wt2[3];
  u16 *whi[3], *wlo[3];
  whi[0] = (u16*)alloc((size_t)NCOLS * 128 * 2);
  wlo[0] = (u16*)alloc((size_t)NCOLS * 128 * 2);
  whi[1] = (u16*)alloc((size_t)NCOLS * 64 * 2);
  wlo[1] = (u16*)alloc((size_t)NCOLS * 64 * 2);
  whi[2] = (u16*)alloc((size_t)NCOLS * 64 * 2);
  wlo[2] = (u16*)alloc((size_t)NCOLS * 64 * 2);
  for (int L = 0; L < 3; ++L) bb[L] = (float*)alloc((size_t)NCOLS * 4);
  for (int L = 0; L < 3; ++L) Wt2[L] = (float*)alloc((size_t)64 * 256 * 4);

  // Workspace overflow guard (all-zero output == error 1.65625 signature).
  if ((size_t)(p - (char*)d_ws) > ws_size) {
    hipMemsetAsync(d_out, 0, (size_t)out_size * 4, stream);
    return;
  }

  // Optional ea_csr buffer (205 MB).
  float* ea_csr = nullptr;
  int use_csr = 0;
  {
    size_t need = (size_t)(p - (char*)d_ws) + (size_t)NE * 64 * 4 + 256;
    if (need <= ws_size) {
      ea_csr = (float*)alloc((size_t)NE * 64 * 4);
      use_csr = 1;
    }
  }

  hipMemsetAsync(deg, 0, (size_t)NN * 4, stream);
  hipMemsetAsync(cursor, 0, (size_t)NN * 4, stream);
  hipMemsetAsync(flag, 0, 4, stream);

  detect_i64<<<8, 256, 0, stream>>>((const int*)ei, flag);
  extract_edges<<<2048, 256, 0, stream>>>(ei, flag, src32, dst32, NE);

  hist_kernel<<<2048, 256, 0, stream>>>(dst32, deg, NE);
  int nchunks = (NN + SCHUNK - 1) / SCHUNK;
  scanA<<<nchunks, SCHUNK, 0, stream>>>(deg, row_ptr, csum, NN);
  scanB<<<1, 64, 0, stream>>>(csum, nchunks);
  scanC<<<nchunks, SCHUNK, 0, stream>>>(row_ptr, csum, NN);
  scatter_kernel<<<2048, 256, 0, stream>>>(src32, dst32, row_ptr, cursor, src_sorted, eid_sorted, NE);
  sort_lists<<<(NN + 255) / 256, 256, 0, stream>>>(row_ptr, src_sorted, eid_sorted, NN);
  if (use_csr)
    ea_gather<<<2048, 256, 0, stream>>>(eid_sorted, ea, ea_csr, NE);

  cvt_split<<<2048, 256, 0, stream>>>(x, xhi, xlo, NN * 128);

  for (int L = 0; L < 3; ++L) {
    int fin = (L == 0) ? 128 : 64;
    prep_wt_split<<<(NCOLS * fin + 255) / 256, 256, 0, stream>>>(
        Wq[L], Wk[L], Wv[L], We[L], Wsk[L], whi[L], wlo[L], fin);
    prep_bias<<<(NCOLS + 255) / 256, 256, 0, stream>>>(bq[L], bk[L], bv[L], We[L], bsk[L], bb[L]);
    prep_wpost<<<64, 256, 0, stream>>>(We[L], Wt2[L]);
  }

  const u16* hi_in = xhi;
  const u16* lo_in = xlo;
  int nblk = (NN + 3) / 4;
  for (int L = 0; L < 3; ++L) {
    int fin = (L == 0) ? 128 : 64;
    dim3 g(17, (NN + 63) / 64);
    node_gemm_mfma<<<g, 256, 0, stream>>>(hi_in, lo_in, whi[L], wlo[L], bb[L],
                                          qq_tab, kv_tab, skip_tab, NN, fin);
    attn_kernel_v6<<<nblk, 256, 0, stream>>>(
        row_ptr, src_sorted, eid_sorted, ea, ea_csr, use_csr,
        qq_tab, kv_tab, avs_tab, awn_tab, NN);
    post_gn<<<(NN + 127) / 128, 256, 0, stream>>>(
        awn_tab, Wt2[L], avs_tab, skip_tab, gnw, gnb,
        (L == 2) ? (float*)d_out : nullptr,
        (L < 2) ? hhi : nullptr, (L < 2) ? hlo : nullptr, NN);
    hi_in = hhi; lo_in = hlo;
  }
}

// Round 15
// 1525.150 us; speedup vs baseline: 1.3296x; 1.0019x over previous
//
#include <hip/hip_runtime.h>
#include <math.h>

#define NN 50000
#define NE 800000
#define NCOLS 1088   // 256 q | 256 k | 256 v | 256 qt | 64 skip   (cols are h*64+d order)

typedef long long i64;
typedef unsigned short u16;
typedef short bf16x8 __attribute__((ext_vector_type(8)));
typedef unsigned short u16x8 __attribute__((ext_vector_type(8)));
typedef float f32x4 __attribute__((ext_vector_type(4)));

static __device__ __forceinline__ float bf2f(u16 u) {
  union { float f; unsigned b; } x; x.b = ((unsigned)u) << 16; return x.f;
}
static __device__ __forceinline__ u16 f2bf(float f) {
  union { float f; unsigned b; } x; x.f = f;
  unsigned r = x.b + 0x7FFFu + ((x.b >> 16) & 1u);
  return (u16)(r >> 16);
}

// ---------------- edge-index dtype probe + extraction (+deg histogram fused) ----------------
__global__ void detect_i64(const int* __restrict__ ei32, int* __restrict__ flag) {
  int i = blockIdx.x * blockDim.x + threadIdx.x;
  if (i < 2048) {
    if (ei32[2 * i + 1] != 0) atomicOr(flag, 1);  // 1 -> data is int32
  }
}

__global__ void extract_edges(const void* __restrict__ ei, const int* __restrict__ flag,
                              int* __restrict__ src32, int* __restrict__ dst32,
                              int* __restrict__ deg, int ne) {
  int is32 = *flag;
  int i = blockIdx.x * blockDim.x + threadIdx.x;
  int st = gridDim.x * blockDim.x;
  if (is32) {
    const int* p = (const int*)ei;
    for (; i < ne; i += st) {
      int d = p[ne + i];
      src32[i] = p[i]; dst32[i] = d;
      atomicAdd(&deg[d], 1);
    }
  } else {
    const i64* p = (const i64*)ei;
    for (; i < ne; i += st) {
      int d = (int)p[ne + i];
      src32[i] = (int)p[i]; dst32[i] = d;
      atomicAdd(&deg[d], 1);
    }
  }
}

// ---------------- CSR build ----------------
#define SCHUNK 1024
__global__ void scanA(const int* __restrict__ deg, int* __restrict__ row_ptr,
                      int* __restrict__ csum, int n) {
  __shared__ int buf[SCHUNK];
  int c = blockIdx.x, t = threadIdx.x;
  int idx = c * SCHUNK + t;
  int v = (idx < n) ? deg[idx] : 0;
  buf[t] = v;
  __syncthreads();
  for (int off = 1; off < SCHUNK; off <<= 1) {
    int x = (t >= off) ? buf[t - off] : 0;
    __syncthreads();
    buf[t] += x;
    __syncthreads();
  }
  if (idx < n) row_ptr[idx + 1] = buf[t];
  if (t == SCHUNK - 1) csum[c] = buf[t];
}

__global__ void scanB(int* __restrict__ csum, int nchunks) {
  if (threadIdx.x == 0 && blockIdx.x == 0) {
    int run = 0;
    for (int c = 0; c < nchunks; ++c) { int v = csum[c]; csum[c] = run; run += v; }
  }
}

__global__ void scanC(int* __restrict__ row_ptr, const int* __restrict__ csum, int n) {
  int c = blockIdx.x, t = threadIdx.x;
  int idx = c * SCHUNK + t;
  if (idx < n) row_ptr[idx + 1] += csum[c];
  if (idx == 0) row_ptr[0] = 0;
}

__global__ void scatter_kernel(const int* __restrict__ src, const int* __restrict__ dst,
                               const int* __restrict__ row_ptr, int* __restrict__ cursor,
                               int* __restrict__ src_sorted, int* __restrict__ eid_sorted, int ne) {
  int i = blockIdx.x * blockDim.x + threadIdx.x;
  int st = gridDim.x * blockDim.x;
  for (; i < ne; i += st) {
    int d = dst[i];
    int pos = row_ptr[d] + atomicAdd(&cursor[d], 1);
    src_sorted[pos] = src[i];
    eid_sorted[pos] = i;
  }
}

// Deterministic order: sort each node's edge list by eid.
__global__ void sort_lists(const int* __restrict__ row_ptr, int* __restrict__ src_sorted,
                           int* __restrict__ eid_sorted, int n) {
  int node = blockIdx.x * blockDim.x + threadIdx.x;
  if (node >= n) return;
  int beg = row_ptr[node], end = row_ptr[node + 1];
  for (int a = beg + 1; a < end; ++a) {
    int e = eid_sorted[a], s = src_sorted[a];
    int b = a - 1;
    while (b >= beg && eid_sorted[b] > e) {
      eid_sorted[b + 1] = eid_sorted[b];
      src_sorted[b + 1] = src_sorted[b];
      --b;
    }
    eid_sorted[b + 1] = e; src_sorted[b + 1] = s;
  }
}

// ---------------- ea pre-gather into CSR order (fp32 — precision mandatory) ----------
__global__ void ea_gather(const int* __restrict__ eid_sorted, const float* __restrict__ ea,
                          float* __restrict__ ea_csr, int ne) {
  long total = (long)ne * 16;
  long st = (long)gridDim.x * blockDim.x;
  for (long i = (long)blockIdx.x * blockDim.x + threadIdx.x; i < total; i += st) {
    int j = (int)(i >> 4);
    int c = (int)(i & 15);
    int e = eid_sorted[j];
    ((float4*)ea_csr)[i] = ((const float4*)ea)[(size_t)e * 16 + c];
  }
}

// ---------------- split fp32 -> bf16 hi + bf16 lo (for x input) ----------------
__global__ void cvt_split(const float* __restrict__ in, u16* __restrict__ hi,
                          u16* __restrict__ lo, int nElem) {
  int i = blockIdx.x * blockDim.x + threadIdx.x;
  int st = gridDim.x * blockDim.x;
  for (; i < nElem; i += st) {
    float v = in[i];
    u16 h = f2bf(v);
    hi[i] = h;
    lo[i] = f2bf(v - bf2f(h));
  }
}

// ---------------- weight prep: directly emit split hi/lo (head-major cols) ----------------
__global__ void prep_wt_split(const float* __restrict__ Wq, const float* __restrict__ Wk,
                              const float* __restrict__ Wv, const float* __restrict__ We,
                              const float* __restrict__ Wsk,
                              u16* __restrict__ whi, u16* __restrict__ wlo, int fin) {
  int i = blockIdx.x * blockDim.x + threadIdx.x;
  if (i >= NCOLS * fin) return;
  int col = i / fin, k = i % fin;
  float val;
  if (col < 768) {
    const float* W = (col < 256) ? Wq : (col < 512) ? Wk : Wv;
    val = W[k * 256 + (col & 255)];
  } else if (col < 1024) {
    int idx = col - 768; int h = idx >> 6, ce = idx & 63;
    float a = 0.f;
    for (int d = 0; d < 64; ++d) a += Wq[k * 256 + h * 64 + d] * We[ce * 256 + h * 64 + d];
    val = a;
  } else {
    val = Wsk[k * 64 + (col - 1024)];
  }
  size_t idx2 = (size_t)col * fin + k;
  u16 h = f2bf(val);
  whi[idx2] = h;
  wlo[idx2] = f2bf(val - bf2f(h));
}

__global__ void prep_bias(const float* __restrict__ bq, const float* __restrict__ bk,
                          const float* __restrict__ bv, const float* __restrict__ We,
                          const float* __restrict__ bsk, float* __restrict__ bb) {
  int col = blockIdx.x * blockDim.x + threadIdx.x;
  if (col >= NCOLS) return;
  float val;
  if (col < 768) {
    const float* b = (col < 256) ? bq : (col < 512) ? bk : bv;
    val = b[col & 255];
  } else if (col < 1024) {
    int idx = col - 768; int h = idx >> 6, ce = idx & 63;
    float a = 0.f;
    for (int d = 0; d < 64; ++d) a += bq[h * 64 + d] * We[ce * 256 + h * 64 + d];
    val = a;
  } else {
    val = bsk[col - 1024];
  }
  bb[col] = val;
}

// Wpost for the deferred West GEMM: Wt2[col][k], k = h*64+ce, value We[ce][h*64+col]
__global__ void prep_wpost(const float* __restrict__ We, float* __restrict__ Wt2) {
  int i = blockIdx.x * blockDim.x + threadIdx.x;
  if (i >= 64 * 256) return;
  int col = i >> 8, k = i & 255;
  int h = k >> 6, ce = k & 63;
  Wt2[i] = We[ce * 256 + h * 64 + col];
}

// ---------------- split-bf16 MFMA node GEMM: out = X @ Wt^T + b ----------------
__global__ __launch_bounds__(256) void node_gemm_mfma(
    const u16* __restrict__ Xhi, const u16* __restrict__ Xlo,
    const u16* __restrict__ Whi, const u16* __restrict__ Wlo,
    const float* __restrict__ bb,
    float* __restrict__ qq_tab, float* __restrict__ kv_tab,
    float* __restrict__ skip_tab, int n, int fin) {
  __shared__ __align__(16) u16 Ah[64][72];
  __shared__ __align__(16) u16 Al[64][72];
  __shared__ __align__(16) u16 Bh[64][72];
  __shared__ __align__(16) u16 Bl[64][72];
  int tid = threadIdx.x, wave = tid >> 6, lane = tid & 63;
  int c0 = blockIdx.x * 64, m0 = blockIdx.y * 64;
  f32x4 acc[4];
  #pragma unroll
  for (int i = 0; i < 4; ++i) acc[i] = (f32x4){0.f, 0.f, 0.f, 0.f};

  int lr = tid >> 2, sg = (tid & 3) * 16;
  for (int k0 = 0; k0 < fin; k0 += 64) {
    u16x8 z = {0, 0, 0, 0, 0, 0, 0, 0};
    u16x8 a0 = z, a1 = z, l0 = z, l1 = z;
    if (m0 + lr < n) {
      const u16* ph = &Xhi[(size_t)(m0 + lr) * fin + k0 + sg];
      a0 = *(const u16x8*)ph; a1 = *(const u16x8*)(ph + 8);
      const u16* pl = &Xlo[(size_t)(m0 + lr) * fin + k0 + sg];
      l0 = *(const u16x8*)pl; l1 = *(const u16x8*)(pl + 8);
    }
    *(u16x8*)&Ah[lr][sg] = a0; *(u16x8*)&Ah[lr][sg + 8] = a1;
    *(u16x8*)&Al[lr][sg] = l0; *(u16x8*)&Al[lr][sg + 8] = l1;
    {
      const u16* ph = &Whi[(size_t)(c0 + lr) * fin + k0 + sg];
      *(u16x8*)&Bh[lr][sg] = *(const u16x8*)ph;
      *(u16x8*)&Bh[lr][sg + 8] = *(const u16x8*)(ph + 8);
      const u16* pl = &Wlo[(size_t)(c0 + lr) * fin + k0 + sg];
      *(u16x8*)&Bl[lr][sg] = *(const u16x8*)pl;
      *(u16x8*)&Bl[lr][sg + 8] = *(const u16x8*)(pl + 8);
    }
    __syncthreads();
    int arow = wave * 16 + (lane & 15);
    int kb = (lane >> 4) * 8;
    #pragma unroll
    for (int ks = 0; ks < 2; ++ks) {
      bf16x8 ah = *(const bf16x8*)&Ah[arow][ks * 32 + kb];
      bf16x8 al_ = *(const bf16x8*)&Al[arow][ks * 32 + kb];
      #pragma unroll
      for (int nf = 0; nf < 4; ++nf) {
        bf16x8 bh = *(const bf16x8*)&Bh[nf * 16 + (lane & 15)][ks * 32 + kb];
        bf16x8 bl = *(const bf16x8*)&Bl[nf * 16 + (lane & 15)][ks * 32 + kb];
        acc[nf] = __builtin_amdgcn_mfma_f32_16x16x32_bf16(ah, bh, acc[nf], 0, 0, 0);
        acc[nf] = __builtin_amdgcn_mfma_f32_16x16x32_bf16(ah, bl, acc[nf], 0, 0, 0);
        acc[nf] = __builtin_amdgcn_mfma_f32_16x16x32_bf16(al_, bh, acc[nf], 0, 0, 0);
      }
    }
    __syncthreads();
  }
  int rbase = m0 + wave * 16 + (lane >> 4) * 4;
  int cl = lane & 15;
  #pragma unroll
  for (int nf = 0; nf < 4; ++nf) {
    int col = c0 + nf * 16 + cl;
    float bias = bb[col];
    #pragma unroll
    for (int r = 0; r < 4; ++r) {
      int row = rbase + r;
      if (row >= n) continue;
      float val = acc[nf][r] + bias;
      if (col < 256)        qq_tab[(size_t)row * 512 + col] = val;           // q
      else if (col < 768)   kv_tab[(size_t)row * 512 + col - 256] = val;     // k | v
      else if (col < 1024)  qq_tab[(size_t)row * 512 + col - 512] = val;     // qt
      else                  skip_tab[(size_t)row * 64 + col - 1024] = val;
    }
  }
}

// ---------------- attention v6: 1 node/wave, no West matvec (all fp32) ----------------
__global__ __launch_bounds__(256) void attn_kernel_v6(
    const int* __restrict__ row_ptr, const int* __restrict__ src_sorted,
    const int* __restrict__ eid_sorted, const float* __restrict__ ea,
    const float* __restrict__ ea_csr, int use_csr,
    const float* __restrict__ qq_tab, const float* __restrict__ kv_tab,
    float* __restrict__ avs_tab, float* __restrict__ awn_tab, int n) {
  int tid = threadIdx.x;
  int wave = tid >> 6, lane = tid & 63;
  int c16 = lane & 15;
  const float4* qq4 = (const float4*)qq_tab;
  const float4* kv4 = (const float4*)kv_tab;
  const float4* ec4 = (const float4*)ea_csr;
  const float4* e4p = (const float4*)ea;

  int node = blockIdx.x * 4 + wave;
  if (node >= n) return;
  int beg = row_ptr[node];
  int deg = row_ptr[node + 1] - beg;

  float4 q4 = qq4[(size_t)node * 128 + lane];
  float4 t4 = qq4[(size_t)node * 128 + 64 + lane];

  float m = -INFINITY, s = 0.f;
  float4 av = make_float4(0.f, 0.f, 0.f, 0.f);
  float4 aw = make_float4(0.f, 0.f, 0.f, 0.f);

#define LDE(j_, K_, V_, E_)                                   \
  {                                                           \
    int jc = (j_); int jm = beg + deg - 1;                    \
    if (jc > jm) jc = jm;                                     \
    int s_ = src_sorted[jc];                                  \
    const float4* kr = kv4 + (size_t)s_ * 128;                \
    K_ = kr[lane]; V_ = kr[64 + lane];                        \
    if (use_csr) E_ = ec4[(size_t)jc * 16 + c16];             \
    else { int e_ = eid_sorted[jc];                           \
           E_ = e4p[(size_t)e_ * 16 + c16]; }                 \
  }

#define PROC(K_, V_, E_)                                      \
  {                                                           \
    float p = q4.x * K_.x + q4.y * K_.y + q4.z * K_.z + q4.w * K_.w \
            + t4.x * E_.x + t4.y * E_.y + t4.z * E_.z + t4.w * E_.w; \
    p += __shfl_xor(p, 1);                                    \
    p += __shfl_xor(p, 2);                                    \
    p += __shfl_xor(p, 4);                                    \
    p += __shfl_xor(p, 8);                                    \
    p *= 0.125f;                                              \
    float d_ = p - m;                                         \
    float e_ = __expf(-fabsf(d_));                            \
    float sc = d_ > 0.f ? e_ : 1.f;                           \
    float pp = d_ > 0.f ? 1.f : e_;                           \
    m = fmaxf(m, p);                                          \
    s = s * sc + pp;                                          \
    av.x = av.x * sc + pp * V_.x; av.y = av.y * sc + pp * V_.y; \
    av.z = av.z * sc + pp * V_.z; av.w = av.w * sc + pp * V_.w; \
    aw.x = aw.x * sc + pp * E_.x; aw.y = aw.y * sc + pp * E_.y; \
    aw.z = aw.z * sc + pp * E_.z; aw.w = aw.w * sc + pp * E_.w; \
  }

  if (deg > 0) {
    float4 KA, VA, EA, KB, VB, EB;
    LDE(beg + 0, KA, VA, EA);
    LDE(beg + 1, KB, VB, EB);
    int t = 0;
    for (; t + 1 < deg; t += 2) {
      {
        float4 nK, nV, nE;
        LDE(beg + t + 2, nK, nV, nE);
        PROC(KA, VA, EA);
        KA = nK; VA = nV; EA = nE;
      }
      {
        float4 nK, nV, nE;
        LDE(beg + t + 3, nK, nV, nE);
        PROC(KB, VB, EB);
        KB = nK; VB = nV; EB = nE;
      }
    }
    if (t < deg) PROC(KA, VA, EA);
  }

  float inv = s > 0.f ? 1.f / s : 0.f;
  float4 awn = make_float4(aw.x * inv, aw.y * inv, aw.z * inv, aw.w * inv);
  float4 avn = make_float4(av.x * inv, av.y * inv, av.z * inv, av.w * inv);

  ((float4*)awn_tab)[(size_t)node * 64 + lane] = awn;

  avn.x += __shfl_xor(avn.x, 16); avn.y += __shfl_xor(avn.y, 16);
  avn.z += __shfl_xor(avn.z, 16); avn.w += __shfl_xor(avn.w, 16);
  avn.x += __shfl_xor(avn.x, 32); avn.y += __shfl_xor(avn.y, 32);
  avn.z += __shfl_xor(avn.z, 32); avn.w += __shfl_xor(avn.w, 32);
  if (lane < 16)
    ((float4*)avs_tab)[(size_t)node * 16 + c16] = avn;
}

// ---------------- post GEMM + fused head-mean/skip/GN/GELU (+ optional bf16 split out) ----
__global__ __launch_bounds__(256) void post_gn(
    const float* __restrict__ A, const float* __restrict__ B,
    const float* __restrict__ avs, const float* __restrict__ skip,
    const float* __restrict__ gnw, const float* __restrict__ gnb,
    float* __restrict__ out_f32, u16* __restrict__ out_hi, u16* __restrict__ out_lo, int n) {
  __shared__ __align__(16) float Xs[128][68];
  __shared__ __align__(16) float Ws[64][68];
  int tid = threadIdx.x;
  int tx = tid & 15, ty = tid >> 4;
  int m0 = blockIdx.x * 128;
  float acc[8][4];
  #pragma unroll
  for (int i = 0; i < 8; ++i)
    #pragma unroll
    for (int j = 0; j < 4; ++j) acc[i][j] = 0.f;

  for (int k0 = 0; k0 < 256; k0 += 64) {
    #pragma unroll
    for (int p = 0; p < 8; ++p) {
      int r = ty + 16 * p;
      float4 xv = make_float4(0.f, 0.f, 0.f, 0.f);
      if (m0 + r < n) xv = *(const float4*)&A[(size_t)(m0 + r) * 256 + k0 + tx * 4];
      *(float4*)&Xs[r][tx * 4] = xv;
    }
    #pragma unroll
    for (int p = 0; p < 4; ++p) {
      int r = ty + 16 * p;
      float4 wv = *(const float4*)&B[(size_t)r * 256 + k0 + tx * 4];
      *(float4*)&Ws[r][tx * 4] = wv;
    }
    __syncthreads();
    #pragma unroll 4
    for (int kk = 0; kk < 64; kk += 4) {
      float4 a[8], b[4];
      #pragma unroll
      for (int i = 0; i < 8; ++i) a[i] = *(const float4*)&Xs[ty + 16 * i][kk];
      #pragma unroll
      for (int j = 0; j < 4; ++j) b[j] = *(const float4*)&Ws[tx + 16 * j][kk];
      #pragma unroll
      for (int i = 0; i < 8; ++i)
        #pragma unroll
        for (int j = 0; j < 4; ++j) {
          acc[i][j] = fmaf(a[i].x, b[j].x, acc[i][j]);
          acc[i][j] = fmaf(a[i].y, b[j].y, acc[i][j]);
          acc[i][j] = fmaf(a[i].z, b[j].z, acc[i][j]);
          acc[i][j] = fmaf(a[i].w, b[j].w, acc[i][j]);
        }
    }
    __syncthreads();
  }
  #pragma unroll
  for (int j = 0; j < 4; ++j)
    #pragma unroll
    for (int i = 0; i < 8; ++i)
      Xs[ty + 16 * i][tx + 16 * j] = acc[i][j];
  __syncthreads();

  #pragma unroll
  for (int rep = 0; rep < 8; ++rep) {
    int id = tid + 256 * rep;
    int rl = id >> 4, grp = id & 15;
    int row = m0 + rl;
    if (row >= n) continue;
    float4 a = ((const float4*)avs)[(size_t)row * 16 + grp];
    float4 sk = ((const float4*)skip)[(size_t)row * 16 + grp];
    float4 gw = ((const float4*)gnw)[grp];
    float4 gb = ((const float4*)gnb)[grp];
    float p0 = Xs[rl][grp * 4 + 0], p1 = Xs[rl][grp * 4 + 1];
    float p2 = Xs[rl][grp * 4 + 2], p3 = Xs[rl][grp * 4 + 3];
    float v0 = 0.25f * (a.x + p0) + sk.x;
    float v1 = 0.25f * (a.y + p1) + sk.y;
    float v2 = 0.25f * (a.z + p2) + sk.z;
    float v3 = 0.25f * (a.w + p3) + sk.w;
    float mu = ((v0 + v1) + (v2 + v3)) * 0.25f;
    float d0 = v0 - mu, d1 = v1 - mu, d2 = v2 - mu, d3 = v3 - mu;
    float var = ((d0 * d0 + d1 * d1) + (d2 * d2 + d3 * d3)) * 0.25f;
    float r = rsqrtf(var + 1e-5f);
    float y0 = d0 * r * gw.x + gb.x;
    float y1 = d1 * r * gw.y + gb.y;
    float y2 = d2 * r * gw.z + gb.z;
    float y3 = d3 * r * gw.w + gb.w;
    #define GELU(y) (0.5f * (y) * (1.0f + erff((y) * 0.70710678118654752f)))
    float g0 = GELU(y0), g1 = GELU(y1), g2 = GELU(y2), g3 = GELU(y3);
    if (out_f32) {
      float4 o; o.x = g0; o.y = g1; o.z = g2; o.w = g3;
      ((float4*)out_f32)[(size_t)row * 16 + grp] = o;
    } else {
      u16 h0 = f2bf(g0), h1 = f2bf(g1), h2 = f2bf(g2), h3 = f2bf(g3);
      ushort4 hv; hv.x = h0; hv.y = h1; hv.z = h2; hv.w = h3;
      *(ushort4*)&out_hi[(size_t)row * 64 + grp * 4] = hv;
      ushort4 lv;
      lv.x = f2bf(g0 - bf2f(h0)); lv.y = f2bf(g1 - bf2f(h1));
      lv.z = f2bf(g2 - bf2f(h2)); lv.w = f2bf(g3 - bf2f(h3));
      *(ushort4*)&out_lo[(size_t)row * 64 + grp * 4] = lv;
    }
  }
}

// ---------------- host ----------------
extern "C" void kernel_launch(void* const* d_in, const int* in_sizes, int n_in,
                              void* d_out, int out_size, void* d_ws, size_t ws_size,
                              hipStream_t stream) {
  (void)in_sizes; (void)n_in;
  const float* x = (const float*)d_in[0];
  const void* ei = d_in[1];
  const float* ea = (const float*)d_in[2];
  const float *Wq[3], *bq[3], *Wk[3], *bk[3], *Wv[3], *bv[3], *We[3], *Wsk[3], *bsk[3];
  for (int L = 0; L < 3; ++L) {
    int b = 3 + 9 * L;
    Wq[L] = (const float*)d_in[b + 0]; bq[L] = (const float*)d_in[b + 1];
    Wk[L] = (const float*)d_in[b + 2]; bk[L] = (const float*)d_in[b + 3];
    Wv[L] = (const float*)d_in[b + 4]; bv[L] = (const float*)d_in[b + 5];
    We[L] = (const float*)d_in[b + 6]; Wsk[L] = (const float*)d_in[b + 7];
    bsk[L] = (const float*)d_in[b + 8];
  }
  const float* gnw = (const float*)d_in[30];
  const float* gnb = (const float*)d_in[31];

  char* p = (char*)d_ws;
  auto alloc = [&](size_t bytes) -> void* {
    void* r = (void*)p;
    p += (bytes + 255) & ~(size_t)255;
    return r;
  };
  float* qq_tab = (float*)alloc((size_t)NN * 512 * 4);
  float* kv_tab = (float*)alloc((size_t)NN * 512 * 4);
  float* skip_tab = (float*)alloc((size_t)NN * 64 * 4);
  float* avs_tab = (float*)alloc((size_t)NN * 64 * 4);
  float* awn_tab = (float*)alloc((size_t)NN * 256 * 4);
  u16* xhi = (u16*)alloc((size_t)NN * 128 * 2);
  u16* xlo = (u16*)alloc((size_t)NN * 128 * 2);
  u16* hhi = (u16*)alloc((size_t)NN * 64 * 2);
  u16* hlo = (u16*)alloc((size_t)NN * 64 * 2);
  int* row_ptr = (int*)alloc((size_t)(NN + 1) * 4);
  int* deg = (int*)alloc((size_t)NN * 4);
  int* cursor = (int*)alloc((size_t)NN * 4);
  int* csum = (int*)alloc(1024 * 4);
  int* src_sorted = (int*)alloc((size_t)NE * 4);
  int* eid_sorted = (int*)alloc((size_t)NE * 4);
  int* src32 = (int*)alloc((size_t)NE * 4);
  int* dst32 = (int*)alloc((size_t)NE * 4);
  int* flag = (int*)alloc(256);
  float* bb[3]; float* Wt2[3];
  u16 *whi[3], *wlo[3];
  whi[0] = (u16*)alloc((size_t)NCOLS * 128 * 2);
  wlo[0] = (u16*)alloc((size_t)NCOLS * 128 * 2);
  whi[1] = (u16*)alloc((size_t)NCOLS * 64 * 2);
  wlo[1] = (u16*)alloc((size_t)NCOLS * 64 * 2);
  whi[2] = (u16*)alloc((size_t)NCOLS * 64 * 2);
  wlo[2] = (u16*)alloc((size_t)NCOLS * 64 * 2);
  for (int L = 0; L < 3; ++L) bb[L] = (float*)alloc((size_t)NCOLS * 4);
  for (int L = 0; L < 3; ++L) Wt2[L] = (float*)alloc((size_t)64 * 256 * 4);

  // Workspace overflow guard (all-zero output == error 1.65625 signature).
  if ((size_t)(p - (char*)d_ws) > ws_size) {
    hipMemsetAsync(d_out, 0, (size_t)out_size * 4, stream);
    return;
  }

  // Optional ea_csr buffer (205 MB, fp32 CSR-ordered edge attrs).
  float* ea_csr = nullptr;
  int use_csr = 0;
  {
    size_t need = (size_t)(p - (char*)d_ws) + (size_t)NE * 64 * 4 + 256;
    if (need <= ws_size) {
      ea_csr = (float*)alloc((size_t)NE * 64 * 4);
      use_csr = 1;
    }
  }

  hipMemsetAsync(deg, 0, (size_t)NN * 4, stream);
  hipMemsetAsync(cursor, 0, (size_t)NN * 4, stream);
  hipMemsetAsync(flag, 0, 4, stream);

  detect_i64<<<8, 256, 0, stream>>>((const int*)ei, flag);
  extract_edges<<<2048, 256, 0, stream>>>(ei, flag, src32, dst32, deg, NE);

  int nchunks = (NN + SCHUNK - 1) / SCHUNK;
  scanA<<<nchunks, SCHUNK, 0, stream>>>(deg, row_ptr, csum, NN);
  scanB<<<1, 64, 0, stream>>>(csum, nchunks);
  scanC<<<nchunks, SCHUNK, 0, stream>>>(row_ptr, csum, NN);
  scatter_kernel<<<2048, 256, 0, stream>>>(src32, dst32, row_ptr, cursor, src_sorted, eid_sorted, NE);
  sort_lists<<<(NN + 255) / 256, 256, 0, stream>>>(row_ptr, src_sorted, eid_sorted, NN);
  if (use_csr)
    ea_gather<<<2048, 256, 0, stream>>>(eid_sorted, ea, ea_csr, NE);

  cvt_split<<<2048, 256, 0, stream>>>(x, xhi, xlo, NN * 128);

  for (int L = 0; L < 3; ++L) {
    int fin = (L == 0) ? 128 : 64;
    prep_wt_split<<<(NCOLS * fin + 255) / 256, 256, 0, stream>>>(
        Wq[L], Wk[L], Wv[L], We[L], Wsk[L], whi[L], wlo[L], fin);
    prep_bias<<<(NCOLS + 255) / 256, 256, 0, stream>>>(bq[L], bk[L], bv[L], We[L], bsk[L], bb[L]);
    prep_wpost<<<64, 256, 0, stream>>>(We[L], Wt2[L]);
  }

  const u16* hi_in = xhi;
  const u16* lo_in = xlo;
  int nblk = (NN + 3) / 4;
  for (int L = 0; L < 3; ++L) {
    int fin = (L == 0) ? 128 : 64;
    dim3 g(17, (NN + 63) / 64);
    node_gemm_mfma<<<g, 256, 0, stream>>>(hi_in, lo_in, whi[L], wlo[L], bb[L],
                                          qq_tab, kv_tab, skip_tab, NN, fin);
    attn_kernel_v6<<<nblk, 256, 0, stream>>>(
        row_ptr, src_sorted, eid_sorted, ea, ea_csr, use_csr,
        qq_tab, kv_tab, avs_tab, awn_tab, NN);
    post_gn<<<(NN + 127) / 128, 256, 0, stream>>>(
        awn_tab, Wt2[L], avs_tab, skip_tab, gnw, gnb,
        (L == 2) ? (float*)d_out : nullptr,
        (L < 2) ? hhi : nullptr, (L < 2) ? hlo : nullptr, NN);
    hi_in = hhi; lo_in = hlo;
  }
}